// Round 14
// baseline (164.716 us; speedup 1.0000x reference)
//
#include <hip/hip_runtime.h>

namespace {

constexpr int Cn   = 256;            // channels
constexpr int Hh   = 128;
constexpr int Ww   = 128;
constexpr int HW   = Hh * Ww;
constexpr int TILE = 16;             // spatial tile edge
constexpr int CCH  = 8;              // channels per LDS chunk
constexpr int NCH  = Cn / CCH;       // 32 chunks
constexpr int HALO = 4;
constexpr int X2T  = 24;             // x2 tile rows/cols staged
constexpr int X2S  = 48;             // padded row stride = 12 granules ->
                                     //  conflict-free b128 reads (r11: 8.26M->1.18M)
constexpr int X2CH = X2T * X2S;      // 1152 floats per channel
constexpr int SC4  = 6;              // float4 per staged row
constexpr int NOFF = 81;

// 576 threads = 9 waves; wave wv <-> window row di = wv (o = 9*wv + dj).
// Lane l: h = l>>2 (tile row), m = l&3 (cols 4m..4m+3).
// r14 = r13's depth-2 staging pipeline with STATIC parity (r13 used rs[pr]
// with runtime pr -> rule-#20 scratch spill, WRITE_SIZE 20.7MB->158MB).
// k-loop unrolled by 2; named rsA/rsB sets; every index compile-time.

__global__ __launch_bounds__(576, 1)
void costvol_kernel(const float* __restrict__ x1,
                    const float* __restrict__ x2,
                    float* __restrict__ out)
{
  __shared__ float s2[2][CCH * X2CH];   // 73,728 B (1 block/CU)

  const int t    = threadIdx.x;
  const int wv   = t >> 6;             // di = 0..8
  const int lane = t & 63;
  const int h    = lane >> 2;          // tile row 0..15
  const int m    = lane & 3;           // pixel group: cols 4m..4m+3

  const int tx = blockIdx.x, ty = blockIdx.y, b = blockIdx.z;
  const int x0 = tx * TILE, y0 = ty * TILE;

  const float* g1 = x1 + (size_t)b * Cn * HW + (size_t)(y0 + h) * Ww + (x0 + 4 * m);
  const float* g2 = x2 + (size_t)b * Cn * HW;

  // ---- float4-granular staging: slot j stages float4 f = t + 576*j ----
  // f -> ch = f/144, rem = f%144, row = rem/6, col4 = rem%6. gx is 4-aligned;
  // a granule is valid iff fully in range (halo granules are fully in or out).
  int  soff[2], swr[2];
  bool sval[2];
#pragma unroll
  for (int j = 0; j < 2; ++j) {
    const int f    = t + 576 * j;      // < 1152 always (2*576 exact)
    const int ch   = f / (X2T * SC4);
    const int rem  = f % (X2T * SC4);
    const int row  = rem / SC4, col4 = rem % SC4;
    const int gy = y0 - HALO + row;
    const int gx = x0 - HALO + 4 * col4;
    sval[j] = ((unsigned)gy < (unsigned)Hh) && (gx >= 0) && (gx + 3 < Ww);
    soff[j] = sval[j] ? (ch * HW + gy * Ww + gx) : 0;
    swr[j]  = ch * X2CH + row * X2S + 4 * col4;
  }

  float4 rsA[2], rsB[2];               // named sets: even / odd chunks
  auto stage_load = [&](int k, float4 rs[2]) {
    const size_t cb = (size_t)(k * CCH) * HW;
#pragma unroll
    for (int j = 0; j < 2; ++j)
      rs[j] = sval[j] ? *reinterpret_cast<const float4*>(g2 + cb + soff[j])
                      : float4{0.f, 0.f, 0.f, 0.f};
  };
  auto stage_write = [&](float* s, const float4 rs[2]) {
#pragma unroll
    for (int j = 0; j < 2; ++j)
      *reinterpret_cast<float4*>(s + swr[j]) = rs[j];
  };

  float acc[9][4];
#pragma unroll
  for (int d = 0; d < 9; ++d)
#pragma unroll
    for (int p = 0; p < 4; ++p) acc[d][p] = 0.0f;

  const int rbase = (h + wv) * X2S + 4 * m;

  // ---- batched half-chunk: load 4 channels' operands, then 144 FMAs ----
  auto half = [&](int k, int hc, const float* sc) {
    float4 a[4];
    float  w[4][12];
#pragma unroll
    for (int cc = 0; cc < 4; ++cc) {
      a[cc] = *reinterpret_cast<const float4*>(
          g1 + (size_t)(k * CCH + 4 * hc + cc) * HW);
      const float* bp = sc + (4 * hc + cc) * X2CH + rbase;
      *reinterpret_cast<float4*>(w[cc])     = *reinterpret_cast<const float4*>(bp);
      *reinterpret_cast<float4*>(w[cc] + 4) = *reinterpret_cast<const float4*>(bp + 4);
      *reinterpret_cast<float4*>(w[cc] + 8) = *reinterpret_cast<const float4*>(bp + 8);
    }
#pragma unroll
    for (int cc = 0; cc < 4; ++cc)
#pragma unroll
      for (int dj = 0; dj < 9; ++dj) {
        acc[dj][0] = fmaf(a[cc].x, w[cc][dj + 0], acc[dj][0]);
        acc[dj][1] = fmaf(a[cc].y, w[cc][dj + 1], acc[dj][1]);
        acc[dj][2] = fmaf(a[cc].z, w[cc][dj + 2], acc[dj][2]);
        acc[dj][3] = fmaf(a[cc].w, w[cc][dj + 3], acc[dj][3]);
      }
  };

  // ---- prologue: chunk0 staged+written, chunk1 loaded ----
  stage_load(0, rsA);
  stage_write(s2[0], rsA);             // waits chunk0 loads (once)
  stage_load(1, rsB);
  __syncthreads();

  for (int i = 0; i < NCH / 2; ++i) {
    const int k = 2 * i;
    // -- phase A: compute chunk k from buf0 --
    stage_write(s2[1], rsB);           // chunk k+1 (loaded a phase ago)
    if (k + 2 < NCH) stage_load(k + 2, rsA);
    half(k, 0, s2[0]);
    half(k, 1, s2[0]);
    __syncthreads();
    // -- phase B: compute chunk k+1 from buf1 --
    if (k + 2 < NCH) stage_write(s2[0], rsA);   // chunk k+2
    if (k + 3 < NCH) stage_load(k + 3, rsB);
    half(k + 1, 0, s2[1]);
    half(k + 1, 1, s2[1]);
    __syncthreads();
  }

  // ---- epilogue: o = 9*di + dj; each (b,o,y,x) written exactly once ----
  const float invc = 1.0f / (float)Cn;
  const int y  = y0 + h;
  const int xb = x0 + 4 * m;
#pragma unroll
  for (int dj = 0; dj < 9; ++dj) {
    const int o = wv * 9 + dj;
    float4 v;
    v.x = acc[dj][0] * invc;
    v.y = acc[dj][1] * invc;
    v.z = acc[dj][2] * invc;
    v.w = acc[dj][3] * invc;
    *reinterpret_cast<float4*>(out + (((size_t)b * NOFF + o) * Hh + y) * Ww + xb) = v;
  }
}

} // namespace

extern "C" void kernel_launch(void* const* d_in, const int* in_sizes, int n_in,
                              void* d_out, int out_size, void* d_ws, size_t ws_size,
                              hipStream_t stream) {
  const float* x1 = (const float*)d_in[0];
  const float* x2 = (const float*)d_in[1];
  float* out = (float*)d_out;

  dim3 grid(Ww / TILE, Hh / TILE, 4);   // 8 x 8 x 4 = 256 blocks (1/CU)
  dim3 block(576);                      // 9 waves: wave wv <-> window row di
  costvol_kernel<<<grid, block, 0, stream>>>(x1, x2, out);
}

// Round 15
// 116.089 us; speedup vs baseline: 1.4189x; 1.4189x over previous
//
#include <hip/hip_runtime.h>

namespace {

constexpr int Cn   = 256;            // channels
constexpr int Hh   = 128;
constexpr int Ww   = 128;
constexpr int HW   = Hh * Ww;
constexpr int TILE = 16;             // spatial tile edge
constexpr int CCH  = 16;             // channels per LDS chunk (r15: 8->16)
constexpr int NCH  = Cn / CCH;       // 16 chunks
constexpr int HALO = 4;
constexpr int X2T  = 24;             // x2 tile rows/cols staged
constexpr int X2S  = 48;             // padded row stride = 12 granules ->
                                     //  conflict-free b128 reads (r11: 8.26M->1.18M)
constexpr int X2CH = X2T * X2S;      // 1152 floats per channel
constexpr int SC4  = 6;              // float4 per staged row
constexpr int NOFF = 81;

// 576 threads = 9 waves; wave wv <-> window row di = wv (o = 9*wv + dj).
// Lane l: h = l>>2 (tile row), m = l&3 (cols 4m..4m+3).
// r15 = r12's exact (spill-free) idiom with CCH 8->16: halves the count of
// staged-load-wait + barrier-resync events (r12: 7.6K cyc/phase vs ~3K pipe
// demand). stage_write moved after ALL compute so the staged loads get the
// full ~3.4K-cyc phase in flight (T14). LDS 147,456 B (fits 160KB; 1 block/CU
// regardless -- 576-thread WGs never pair, r8).
// SPILL LESSONS: no runtime-indexed reg arrays (r13), no arrays passed to
// lambdas as pointers (r14). Only unrolled compile-time indices, by-ref
// captures -- the r12 idiom.

__global__ __launch_bounds__(576, 1)
void costvol_kernel(const float* __restrict__ x1,
                    const float* __restrict__ x2,
                    float* __restrict__ out)
{
  __shared__ float s2[2][CCH * X2CH];   // 147,456 B

  const int t    = threadIdx.x;
  const int wv   = t >> 6;             // di = 0..8
  const int lane = t & 63;
  const int h    = lane >> 2;          // tile row 0..15
  const int m    = lane & 3;           // pixel group: cols 4m..4m+3

  const int tx = blockIdx.x, ty = blockIdx.y, b = blockIdx.z;
  const int x0 = tx * TILE, y0 = ty * TILE;

  const float* g1 = x1 + (size_t)b * Cn * HW + (size_t)(y0 + h) * Ww + (x0 + 4 * m);
  const float* g2 = x2 + (size_t)b * Cn * HW;

  // ---- float4-granular staging: slot j stages float4 f = t + 576*j ----
  // f -> ch = f/144, rem = f%144, row = rem/6, col4 = rem%6. gx 4-aligned;
  // halo granules are fully in- or out-of-range -> whole-granule zero-fill.
  int  soff[4], swr[4];
  bool sval[4];
#pragma unroll
  for (int j = 0; j < 4; ++j) {
    const int f    = t + 576 * j;      // < 2304 always (4*576 exact)
    const int ch   = f / (X2T * SC4);
    const int rem  = f % (X2T * SC4);
    const int row  = rem / SC4, col4 = rem % SC4;
    const int gy = y0 - HALO + row;
    const int gx = x0 - HALO + 4 * col4;
    sval[j] = ((unsigned)gy < (unsigned)Hh) && (gx >= 0) && (gx + 3 < Ww);
    soff[j] = sval[j] ? (ch * HW + gy * Ww + gx) : 0;
    swr[j]  = ch * X2CH + row * X2S + 4 * col4;
  }

  float4 rs0, rs1, rs2, rs3;           // named staged values (no arrays)
  auto stage_load = [&](int k) {
    const size_t cb = (size_t)(k * CCH) * HW;
    rs0 = sval[0] ? *reinterpret_cast<const float4*>(g2 + cb + soff[0])
                  : float4{0.f, 0.f, 0.f, 0.f};
    rs1 = sval[1] ? *reinterpret_cast<const float4*>(g2 + cb + soff[1])
                  : float4{0.f, 0.f, 0.f, 0.f};
    rs2 = sval[2] ? *reinterpret_cast<const float4*>(g2 + cb + soff[2])
                  : float4{0.f, 0.f, 0.f, 0.f};
    rs3 = sval[3] ? *reinterpret_cast<const float4*>(g2 + cb + soff[3])
                  : float4{0.f, 0.f, 0.f, 0.f};
  };
  auto stage_write = [&](int nb) {
    float* s = s2[nb];
    *reinterpret_cast<float4*>(s + swr[0]) = rs0;
    *reinterpret_cast<float4*>(s + swr[1]) = rs1;
    *reinterpret_cast<float4*>(s + swr[2]) = rs2;
    *reinterpret_cast<float4*>(s + swr[3]) = rs3;
  };

  float acc[9][4];
#pragma unroll
  for (int d = 0; d < 9; ++d)
#pragma unroll
    for (int p = 0; p < 4; ++p) acc[d][p] = 0.0f;

  const int rbase = (h + wv) * X2S + 4 * m;

  // ---- batched 4-channel group: load all operands, then 144 FMAs ----
  auto quad = [&](int k, int hc, const float* sc) {
    float4 a[4];
    float  w[4][12];
#pragma unroll
    for (int cc = 0; cc < 4; ++cc) {
      a[cc] = *reinterpret_cast<const float4*>(
          g1 + (size_t)(k * CCH + 4 * hc + cc) * HW);
      const float* bp = sc + (4 * hc + cc) * X2CH + rbase;
      *reinterpret_cast<float4*>(w[cc])     = *reinterpret_cast<const float4*>(bp);
      *reinterpret_cast<float4*>(w[cc] + 4) = *reinterpret_cast<const float4*>(bp + 4);
      *reinterpret_cast<float4*>(w[cc] + 8) = *reinterpret_cast<const float4*>(bp + 8);
    }
#pragma unroll
    for (int cc = 0; cc < 4; ++cc)
#pragma unroll
      for (int dj = 0; dj < 9; ++dj) {
        acc[dj][0] = fmaf(a[cc].x, w[cc][dj + 0], acc[dj][0]);
        acc[dj][1] = fmaf(a[cc].y, w[cc][dj + 1], acc[dj][1]);
        acc[dj][2] = fmaf(a[cc].z, w[cc][dj + 2], acc[dj][2]);
        acc[dj][3] = fmaf(a[cc].w, w[cc][dj + 3], acc[dj][3]);
      }
  };

  stage_load(0);
  stage_write(0);
  __syncthreads();

  for (int k = 0; k < NCH; ++k) {
    if (k + 1 < NCH) stage_load(k + 1);        // issue at phase top: in flight
                                               //  for the whole ~3.4K-cyc phase
    const float* sc = s2[k & 1];
    quad(k, 0, sc);
    quad(k, 1, sc);
    quad(k, 2, sc);
    quad(k, 3, sc);
    if (k + 1 < NCH) stage_write((k + 1) & 1); // write late: vmcnt wait covered
    __syncthreads();
  }

  // ---- epilogue: o = 9*di + dj; each (b,o,y,x) written exactly once ----
  const float invc = 1.0f / (float)Cn;
  const int y  = y0 + h;
  const int xb = x0 + 4 * m;
#pragma unroll
  for (int dj = 0; dj < 9; ++dj) {
    const int o = wv * 9 + dj;
    float4 v;
    v.x = acc[dj][0] * invc;
    v.y = acc[dj][1] * invc;
    v.z = acc[dj][2] * invc;
    v.w = acc[dj][3] * invc;
    *reinterpret_cast<float4*>(out + (((size_t)b * NOFF + o) * Hh + y) * Ww + xb) = v;
  }
}

} // namespace

extern "C" void kernel_launch(void* const* d_in, const int* in_sizes, int n_in,
                              void* d_out, int out_size, void* d_ws, size_t ws_size,
                              hipStream_t stream) {
  const float* x1 = (const float*)d_in[0];
  const float* x2 = (const float*)d_in[1];
  float* out = (float*)d_out;

  dim3 grid(Ww / TILE, Hh / TILE, 4);   // 8 x 8 x 4 = 256 blocks (1/CU)
  dim3 block(576);                      // 9 waves: wave wv <-> window row di
  costvol_kernel<<<grid, block, 0, stream>>>(x1, x2, out);
}

// Round 16
// 79.490 us; speedup vs baseline: 2.0722x; 1.4604x over previous
//
#include <hip/hip_runtime.h>

namespace {

constexpr int Cn   = 256;
constexpr int Hh   = 128;
constexpr int Ww   = 128;
constexpr int HW   = Hh * Ww;
constexpr int TILE = 16;
constexpr int CCH  = 8;              // channels per LDS chunk
constexpr int NCH  = Cn / CCH;       // 32 chunks
constexpr int HALO = 4;
constexpr int X2T  = 24;             // staged rows/cols
constexpr int X2S  = 24;             // LINEAR stride (no pad): required by
                                     //  global_load_lds (wave-linear dest).
                                     //  Worst read aliasing 2-way = free (m136);
                                     //  r11 proved conflicts off critical path.
constexpr int X2CH = X2T * X2S;      // 576 floats per channel
constexpr int NOFF = 81;

// 576 threads = 9 waves; wave wv <-> window row di = wv (o = 9*wv + dj).
// Lane l: h = l>>2 (tile row), m = l&3 (cols 4m..4m+3).
// r16 = r12 compute + global_load_lds staging: staged data never touches
// VGPRs (r12-r15 showed every reg-staging widening spills). Slot s = t+576j
// is wave-linear: LDS dest = buf + 256*((t>>6)+9j) floats + lane*16B.
// OOB halo lanes read a 16B zero block (d_ws) with per-chunk increment 0.

__device__ __forceinline__ void gl2lds16(const float* g, float* l) {
  __builtin_amdgcn_global_load_lds(
      (const __attribute__((address_space(1))) void*)g,
      (__attribute__((address_space(3))) void*)l, 16, 0, 0);
}

__global__ __launch_bounds__(576, 1)
void costvol_kernel(const float* __restrict__ x1,
                    const float* __restrict__ x2,
                    const float* __restrict__ zp,   // >=16B of zeros (d_ws)
                    float* __restrict__ out)
{
  __shared__ float s2[2][CCH * X2CH];   // 2 x 18,432 B

  const int t    = threadIdx.x;
  const int wv   = t >> 6;             // di = 0..8
  const int lane = t & 63;
  const int h    = lane >> 2;          // tile row 0..15
  const int m    = lane & 3;           // pixel group: cols 4m..4m+3

  const int tx = blockIdx.x, ty = blockIdx.y, b = blockIdx.z;
  const int x0 = tx * TILE, y0 = ty * TILE;

  const float* g1 = x1 + (size_t)b * Cn * HW + (size_t)(y0 + h) * Ww + (x0 + 4 * m);
  const float* g2 = x2 + (size_t)b * Cn * HW;

  // ---- staging addresses: slot s = t + 576*j; s -> ch=s/144, row, col4 ----
  // gx 4-aligned; halo granules fully in- or out-of-range -> zero via zp.
  const float* gp0;  size_t inc0;
  const float* gp1;  size_t inc1;
  {
    const int s = t, ch = s / 144, rem = s % 144, row = rem / 6, c4 = rem % 6;
    const int gy = y0 - HALO + row, gx = x0 - HALO + 4 * c4;
    const bool ok = ((unsigned)gy < (unsigned)Hh) && (gx >= 0) && (gx + 3 < Ww);
    gp0  = ok ? (g2 + (size_t)ch * HW + (size_t)gy * Ww + gx) : zp;
    inc0 = ok ? (size_t)(CCH * HW) : 0;
  }
  {
    const int s = t + 576, ch = s / 144, rem = s % 144, row = rem / 6, c4 = rem % 6;
    const int gy = y0 - HALO + row, gx = x0 - HALO + 4 * c4;
    const bool ok = ((unsigned)gy < (unsigned)Hh) && (gx >= 0) && (gx + 3 < Ww);
    gp1  = ok ? (g2 + (size_t)ch * HW + (size_t)gy * Ww + gx) : zp;
    inc1 = ok ? (size_t)(CCH * HW) : 0;
  }

  // wave-uniform LDS float offsets for the two slot regions
  const int lds0 = (t >> 6) * 256;          // region (wv + 9*0) * 64 slots
  const int lds1 = lds0 + 9 * 256;          // region (wv + 9*1) * 64 slots

  float acc[9][4];
#pragma unroll
  for (int d = 0; d < 9; ++d)
#pragma unroll
    for (int p = 0; p < 4; ++p) acc[d][p] = 0.0f;

  const int rbase = (h + wv) * X2S + 4 * m;

  // ---- batched 4-channel group: load operands, then 144 FMAs (r12 form) ----
  auto quad = [&](int k, int hc, const float* sc) {
    float4 a[4];
    float  w[4][12];
#pragma unroll
    for (int cc = 0; cc < 4; ++cc) {
      a[cc] = *reinterpret_cast<const float4*>(
          g1 + (size_t)(k * CCH + 4 * hc + cc) * HW);
      const float* bp = sc + (4 * hc + cc) * X2CH + rbase;
      *reinterpret_cast<float4*>(w[cc])     = *reinterpret_cast<const float4*>(bp);
      *reinterpret_cast<float4*>(w[cc] + 4) = *reinterpret_cast<const float4*>(bp + 4);
      *reinterpret_cast<float4*>(w[cc] + 8) = *reinterpret_cast<const float4*>(bp + 8);
    }
#pragma unroll
    for (int cc = 0; cc < 4; ++cc)
#pragma unroll
      for (int dj = 0; dj < 9; ++dj) {
        acc[dj][0] = fmaf(a[cc].x, w[cc][dj + 0], acc[dj][0]);
        acc[dj][1] = fmaf(a[cc].y, w[cc][dj + 1], acc[dj][1]);
        acc[dj][2] = fmaf(a[cc].z, w[cc][dj + 2], acc[dj][2]);
        acc[dj][3] = fmaf(a[cc].w, w[cc][dj + 3], acc[dj][3]);
      }
  };

  // ---- prologue: stage chunk 0 ----
  gl2lds16(gp0, &s2[0][lds0]);  gp0 += inc0;
  gl2lds16(gp1, &s2[0][lds1]);  gp1 += inc1;
  asm volatile("s_waitcnt vmcnt(0)" ::: "memory");
  __syncthreads();

  for (int k = 0; k < NCH; ++k) {
    if (k + 1 < NCH) {                       // issue next chunk at phase top:
      float* nb = s2[(k + 1) & 1];           //  zero registers, full-phase flight
      gl2lds16(gp0, nb + lds0);  gp0 += inc0;
      gl2lds16(gp1, nb + lds1);  gp1 += inc1;
    }
    const float* sc = s2[k & 1];
    quad(k, 0, sc);
    quad(k, 1, sc);
    asm volatile("s_waitcnt vmcnt(0)" ::: "memory");  // next chunk landed
    __syncthreads();
  }

  // ---- epilogue: o = 9*di + dj; each (b,o,y,x) written exactly once ----
  const float invc = 1.0f / (float)Cn;
  const int y  = y0 + h;
  const int xb = x0 + 4 * m;
#pragma unroll
  for (int dj = 0; dj < 9; ++dj) {
    const int o = wv * 9 + dj;
    float4 v;
    v.x = acc[dj][0] * invc;
    v.y = acc[dj][1] * invc;
    v.z = acc[dj][2] * invc;
    v.w = acc[dj][3] * invc;
    *reinterpret_cast<float4*>(out + (((size_t)b * NOFF + o) * Hh + y) * Ww + xb) = v;
  }
}

} // namespace

extern "C" void kernel_launch(void* const* d_in, const int* in_sizes, int n_in,
                              void* d_out, int out_size, void* d_ws, size_t ws_size,
                              hipStream_t stream) {
  const float* x1 = (const float*)d_in[0];
  const float* x2 = (const float*)d_in[1];
  float* out = (float*)d_out;

  // 16B zero block for OOB halo staging (capture-legal async memset)
  hipMemsetAsync(d_ws, 0, 256, stream);

  dim3 grid(Ww / TILE, Hh / TILE, 4);   // 8 x 8 x 4 = 256 blocks (1/CU)
  dim3 block(576);                      // 9 waves: wave wv <-> window row di
  costvol_kernel<<<grid, block, 0, stream>>>(x1, x2, (const float*)d_ws, out);
}